// Round 1
// baseline (1867.084 us; speedup 1.0000x reference)
//
#include <hip/hip_runtime.h>
#include <math.h>

#define BATCH 32768
#define D 64

// Each ntn(a, c, T): out[k,b] = tanh( sum_ij a[b,i] T[k,i,j] c[b,j] + W[k,0:64]·a + W[k,64:128]·c + bias[k] )
//
// Block = 512 threads = 8 waves. Wave w handles k in [w*8, w*8+8) (wave-uniform -> T rows come
// in via scalar loads, feeding v_fmac with an SGPR operand). Lanes = 64 consecutive batch rows.
// The "c"-side row sits in 64 VGPRs; the "a"-side is streamed one element per i.
// Shared-T-dot trick: t(k,i) = T[k,i,:]·c_row is computed once and consumed by two "a" streams.

// ---------------- layer 1, pair (a1, ar): a in {e1, er}, c = p, tensor T1 ----------------
__global__ __launch_bounds__(512, 2)
void ntn_pair_kernel(const float* __restrict__ e1, const float* __restrict__ er,
                     const float* __restrict__ p,
                     const float* __restrict__ T1, const float* __restrict__ W,
                     const float* __restrict__ bias,
                     float* __restrict__ a1T, float* __restrict__ arT)
{
    const int lane = threadIdx.x & 63;
    const int kg   = __builtin_amdgcn_readfirstlane(threadIdx.x >> 6);
    const int b    = blockIdx.x * 64 + lane;

    // p row -> registers (the dotted operand)
    float pr[D];
#pragma unroll
    for (int j = 0; j < D; j += 4) {
        const float4 v = *reinterpret_cast<const float4*>(&p[(size_t)b * D + j]);
        pr[j] = v.x; pr[j + 1] = v.y; pr[j + 2] = v.z; pr[j + 3] = v.w;
    }

    float accA[8], accR[8];
#pragma unroll
    for (int kk = 0; kk < 8; ++kk) {
        const int k = kg * 8 + kk;
        float f0 = 0.f, f1 = 0.f, f2 = 0.f, f3 = 0.f;
#pragma unroll
        for (int j = 0; j < D; j += 4) {
            f0 += W[k * 128 + 64 + j]     * pr[j];
            f1 += W[k * 128 + 64 + j + 1] * pr[j + 1];
            f2 += W[k * 128 + 64 + j + 2] * pr[j + 2];
            f3 += W[k * 128 + 64 + j + 3] * pr[j + 3];
        }
        const float f = (f0 + f1) + (f2 + f3) + bias[k];
        accA[kk] = f; accR[kk] = f;
    }

#pragma unroll 1
    for (int i = 0; i < D; ++i) {
        const float ai = e1[(size_t)b * D + i];
        const float ri = er[(size_t)b * D + i];
#pragma unroll
        for (int kk = 0; kk < 8; ++kk) {
            const int k = kg * 8 + kk;
            const float* __restrict__ Tr = &T1[((size_t)k * D + i) * D];
            float t0 = 0.f, t1 = 0.f, t2 = 0.f, t3 = 0.f;
#pragma unroll
            for (int j = 0; j < D; j += 4) {
                t0 += Tr[j]     * pr[j];
                t1 += Tr[j + 1] * pr[j + 1];
                t2 += Tr[j + 2] * pr[j + 2];
                t3 += Tr[j + 3] * pr[j + 3];
            }
            const float t = (t0 + t1) + (t2 + t3) + W[k * 128 + i];
            accA[kk] += ai * t;
            accR[kk] += ri * t;
        }
    }

#pragma unroll
    for (int kk = 0; kk < 8; ++kk) {
        const int k = kg * 8 + kk;
        a1T[(size_t)k * BATCH + b] = tanhf(accA[kk]);
        arT[(size_t)k * BATCH + b] = tanhf(accR[kk]);
    }
}

// ---------------- layer 1, single (c2): a = p (streamed), c = e2 (in regs), tensor T2 ----------------
__global__ __launch_bounds__(512, 2)
void ntn_c2_kernel(const float* __restrict__ p, const float* __restrict__ e2,
                   const float* __restrict__ T2, const float* __restrict__ W,
                   const float* __restrict__ bias,
                   float* __restrict__ c2T)
{
    const int lane = threadIdx.x & 63;
    const int kg   = __builtin_amdgcn_readfirstlane(threadIdx.x >> 6);
    const int b    = blockIdx.x * 64 + lane;

    float cr[D];
#pragma unroll
    for (int j = 0; j < D; j += 4) {
        const float4 v = *reinterpret_cast<const float4*>(&e2[(size_t)b * D + j]);
        cr[j] = v.x; cr[j + 1] = v.y; cr[j + 2] = v.z; cr[j + 3] = v.w;
    }

    float acc[8];
#pragma unroll
    for (int kk = 0; kk < 8; ++kk) {
        const int k = kg * 8 + kk;
        float f0 = 0.f, f1 = 0.f, f2 = 0.f, f3 = 0.f;
#pragma unroll
        for (int j = 0; j < D; j += 4) {
            f0 += W[k * 128 + 64 + j]     * cr[j];
            f1 += W[k * 128 + 64 + j + 1] * cr[j + 1];
            f2 += W[k * 128 + 64 + j + 2] * cr[j + 2];
            f3 += W[k * 128 + 64 + j + 3] * cr[j + 3];
        }
        acc[kk] = (f0 + f1) + (f2 + f3) + bias[k];
    }

#pragma unroll 1
    for (int i = 0; i < D; ++i) {
        const float pi = p[(size_t)b * D + i];
#pragma unroll
        for (int kk = 0; kk < 8; ++kk) {
            const int k = kg * 8 + kk;
            const float* __restrict__ Tr = &T2[((size_t)k * D + i) * D];
            float t0 = 0.f, t1 = 0.f, t2 = 0.f, t3 = 0.f;
#pragma unroll
            for (int j = 0; j < D; j += 4) {
                t0 += Tr[j]     * cr[j];
                t1 += Tr[j + 1] * cr[j + 1];
                t2 += Tr[j + 2] * cr[j + 2];
                t3 += Tr[j + 3] * cr[j + 3];
            }
            const float t = (t0 + t1) + (t2 + t3) + W[k * 128 + i];
            acc[kk] += pi * t;
        }
    }

#pragma unroll
    for (int kk = 0; kk < 8; ++kk) {
        const int k = kg * 8 + kk;
        c2T[(size_t)k * BATCH + b] = tanhf(acc[kk]);
    }
}

// ---------------- layer 2, pair (u, ur): a in {a1, ar} (streamed), c = c2 (in regs), tensor T3 ----------------
// Writes the final interleaved output: out[b, k, 0] = u, out[b, k, 1] = ur.
__global__ __launch_bounds__(512, 2)
void ntn_out_kernel(const float* __restrict__ a1T, const float* __restrict__ arT,
                    const float* __restrict__ c2T,
                    const float* __restrict__ T3, const float* __restrict__ W,
                    const float* __restrict__ bias,
                    float* __restrict__ out)
{
    const int lane = threadIdx.x & 63;
    const int kg   = __builtin_amdgcn_readfirstlane(threadIdx.x >> 6);
    const int b    = blockIdx.x * 64 + lane;

    // c2 row (feature-major storage -> coalesced)
    float cr[D];
#pragma unroll
    for (int j = 0; j < D; ++j) {
        cr[j] = c2T[(size_t)j * BATCH + b];
    }

    float accU[8], accR[8];
#pragma unroll
    for (int kk = 0; kk < 8; ++kk) {
        const int k = kg * 8 + kk;
        float f0 = 0.f, f1 = 0.f, f2 = 0.f, f3 = 0.f;
#pragma unroll
        for (int j = 0; j < D; j += 4) {
            f0 += W[k * 128 + 64 + j]     * cr[j];
            f1 += W[k * 128 + 64 + j + 1] * cr[j + 1];
            f2 += W[k * 128 + 64 + j + 2] * cr[j + 2];
            f3 += W[k * 128 + 64 + j + 3] * cr[j + 3];
        }
        const float f = (f0 + f1) + (f2 + f3) + bias[k];
        accU[kk] = f; accR[kk] = f;
    }

#pragma unroll 1
    for (int i = 0; i < D; ++i) {
        const float ai = a1T[(size_t)i * BATCH + b];
        const float ri = arT[(size_t)i * BATCH + b];
#pragma unroll
        for (int kk = 0; kk < 8; ++kk) {
            const int k = kg * 8 + kk;
            const float* __restrict__ Tr = &T3[((size_t)k * D + i) * D];
            float t0 = 0.f, t1 = 0.f, t2 = 0.f, t3 = 0.f;
#pragma unroll
            for (int j = 0; j < D; j += 4) {
                t0 += Tr[j]     * cr[j];
                t1 += Tr[j + 1] * cr[j + 1];
                t2 += Tr[j + 2] * cr[j + 2];
                t3 += Tr[j + 3] * cr[j + 3];
            }
            const float t = (t0 + t1) + (t2 + t3) + W[k * 128 + i];
            accU[kk] += ai * t;
            accR[kk] += ri * t;
        }
    }

#pragma unroll
    for (int kk = 0; kk < 8; ++kk) {
        const int k = kg * 8 + kk;
        out[(size_t)b * 128 + k * 2 + 0] = tanhf(accU[kk]);
        out[(size_t)b * 128 + k * 2 + 1] = tanhf(accR[kk]);
    }
}

extern "C" void kernel_launch(void* const* d_in, const int* in_sizes, int n_in,
                              void* d_out, int out_size, void* d_ws, size_t ws_size,
                              hipStream_t stream) {
    const float* e1   = (const float*)d_in[0];
    const float* p    = (const float*)d_in[1];
    const float* e2   = (const float*)d_in[2];
    const float* er   = (const float*)d_in[3];
    const float* T1   = (const float*)d_in[4];
    const float* T2   = (const float*)d_in[5];
    const float* T3   = (const float*)d_in[6];
    const float* W    = (const float*)d_in[7];
    const float* bias = (const float*)d_in[8];
    float* out = (float*)d_out;

    float* ws  = (float*)d_ws;
    float* a1T = ws;                             // (64, B) feature-major
    float* arT = ws + (size_t)BATCH * D;         // (64, B)
    float* c2T = ws + 2 * (size_t)BATCH * D;     // (64, B)

    const dim3 grid(BATCH / 64);
    const dim3 block(512);

    hipLaunchKernelGGL(ntn_pair_kernel, grid, block, 0, stream, e1, er, p, T1, W, bias, a1T, arT);
    hipLaunchKernelGGL(ntn_c2_kernel,  grid, block, 0, stream, p, e2, T2, W, bias, c2T);
    hipLaunchKernelGGL(ntn_out_kernel, grid, block, 0, stream, a1T, arT, c2T, T3, W, bias, out);
}

// Round 2
// 358.278 us; speedup vs baseline: 5.2113x; 5.2113x over previous
//
#include <hip/hip_runtime.h>
#include <hip/hip_bf16.h>
#include <math.h>

#define BATCH 32768

typedef __attribute__((ext_vector_type(8))) short short8v;  // 8 bf16 = 4 VGPR (MFMA A/B frag)
typedef __attribute__((ext_vector_type(4))) float f32x4;    // MFMA C/D frag
typedef unsigned short u16;
typedef unsigned char u8;

#define MFMA16 __builtin_amdgcn_mfma_f32_16x16x32_bf16

// ---- LDS byte offsets (total 128 KiB) ----
#define TB(pp)  ((pp)*16384)      // double-buffered T slice: hi plane 8KB + lo plane 8KB
#define CB      32768             // p tile -> later c2 tile (hi plane +0, lo +8192)
#define E2B     49152             // e2 tile
#define A1B     65536             // e1 tile -> later a1 tile
#define ARB     81920             // er tile -> later ar tile
#define FF0     98304             // ff init [64k][64b] fp32
#define FF1     114688
#define SMBYTES 131072

// ---- d_ws layout (bytes): T splits then W splits; ~3.03 MB total ----
#define WS_T(t) ((size_t)(t)*1048576)   // per tensor: hi 512KB, lo 512KB
#define WS_TLO  524288
#define WS_W    3145728                 // W1h, W1l, W2h, W2l: 4 x 8KB

// swizzled element position within a [64][64] plane (row-major, XOR chunk swizzle)
__device__ __forceinline__ int swzpos(int row, int j) {
    return row * 64 + (j ^ ((row & 7) << 3));
}

// ============================ pre-split kernel ============================
// Splits T1/T2/T3 (64x64x64) and W halves (64x64) into swizzled bf16 hi/lo planes.
__global__ void presplit_kernel(const float* __restrict__ T1, const float* __restrict__ T2,
                                const float* __restrict__ T3, const float* __restrict__ W,
                                u8* __restrict__ ws)
{
    const int idx = blockIdx.x * 256 + threadIdx.x;
    const int NT = 3 * 262144;
    if (idx < NT) {
        const int t = idx >> 18;
        const int r = idx & 262143;
        const int k = r >> 12, i = (r >> 6) & 63, j = r & 63;
        const float* Ts = (t == 0) ? T1 : (t == 1) ? T2 : T3;
        const float x = Ts[r];
        const __hip_bfloat16 h = __float2bfloat16(x);
        const float rem = x - __bfloat162float(h);
        const __hip_bfloat16 lo = __float2bfloat16(rem);
        const int pos = k * 4096 + swzpos(i, j);
        *(__hip_bfloat16*)(ws + WS_T(t) + (size_t)pos * 2) = h;
        *(__hip_bfloat16*)(ws + WS_T(t) + WS_TLO + (size_t)pos * 2) = lo;
    } else if (idx < NT + 8192) {
        const int r = idx - NT;
        const int half = r >> 12;             // 0: W1 (a-side), 1: W2 (c-side)
        const int k = (r >> 6) & 63, j = r & 63;
        const float x = W[k * 128 + half * 64 + j];
        const __hip_bfloat16 h = __float2bfloat16(x);
        const float rem = x - __bfloat162float(h);
        const __hip_bfloat16 lo = __float2bfloat16(rem);
        const int pos = swzpos(k, j);
        u8* plane = ws + WS_W + (size_t)half * 16384;
        *(__hip_bfloat16*)(plane + (size_t)pos * 2) = h;
        *(__hip_bfloat16*)(plane + 8192 + (size_t)pos * 2) = lo;
    }
}

// ============================ device helpers ============================
__device__ __forceinline__ void stage16(const void* g, void* l) {
    __builtin_amdgcn_global_load_lds((const __attribute__((address_space(1))) unsigned int*)g,
                                     (__attribute__((address_space(3))) unsigned int*)l, 16, 0, 0);
}

// stage one 16KB T slice (hi+lo) for k into Tbuf[buf]; each wave moves 4KB (4 x 1KB chunks)
__device__ __forceinline__ void stage_slice(u8* sm, const u8* gh, const u8* gl,
                                            int k, int buf, int w, int l) {
    u8* dst = sm + TB(buf);
    const u8* sh = gh + (size_t)k * 8192;
    const u8* sl = gl + (size_t)k * 8192;
    const int c0 = w * 1024, c1 = (w + 4) * 1024;
    stage16(sh + c0 + l * 16, dst + c0);
    stage16(sh + c1 + l * 16, dst + c1);
    stage16(sl + c0 + l * 16, dst + 8192 + c0);
    stage16(sl + c1 + l * 16, dst + 8192 + c1);
}

// load a B-operand fragment set (hi/lo x 2 K-steps) from an LDS tile plane
__device__ __forceinline__ void bfrags(const u8* plane, int b_local, int lq, int sb,
                                       short8v& h0, short8v& l0, short8v& h1, short8v& l1) {
    const int p0 = b_local * 64 + ((lq * 8) ^ sb);
    const int p1 = b_local * 64 + ((lq * 8 + 32) ^ sb);
    h0 = *(const short8v*)(plane + (size_t)p0 * 2);
    h1 = *(const short8v*)(plane + (size_t)p1 * 2);
    l0 = *(const short8v*)(plane + 8192 + (size_t)p0 * 2);
    l1 = *(const short8v*)(plane + 8192 + (size_t)p1 * 2);
}

// load a W A-operand fragment set from global (pre-split, swizzled)
__device__ __forceinline__ void wfrags(const u16* wh, const u16* wl, int rowA, int lq, int sb,
                                       short8v& h0, short8v& l0, short8v& h1, short8v& l1) {
    const int p0 = rowA * 64 + ((lq * 8) ^ sb);
    const int p1 = rowA * 64 + ((lq * 8 + 32) ^ sb);
    h0 = *(const short8v*)(wh + p0);
    h1 = *(const short8v*)(wh + p1);
    l0 = *(const short8v*)(wl + p0);
    l1 = *(const short8v*)(wl + p1);
}

// split-product accumulate: acc += (Ah+Al)(Bh+Bl) over both K-steps (drop Al*Bl)
__device__ __forceinline__ void mfma6(f32x4& acc,
                                      const short8v& Ah0, const short8v& Al0,
                                      const short8v& Ah1, const short8v& Al1,
                                      const short8v& Bh0, const short8v& Bl0,
                                      const short8v& Bh1, const short8v& Bl1) {
    acc = MFMA16(Ah0, Bh0, acc, 0, 0, 0);
    acc = MFMA16(Ah0, Bl0, acc, 0, 0, 0);
    acc = MFMA16(Al0, Bh0, acc, 0, 0, 0);
    acc = MFMA16(Ah1, Bh1, acc, 0, 0, 0);
    acc = MFMA16(Ah1, Bl1, acc, 0, 0, 0);
    acc = MFMA16(Al1, Bh1, acc, 0, 0, 0);
}

// split a 64x64 fp32 global tile into swizzled hi/lo bf16 LDS planes (coalesced reads)
__device__ __forceinline__ void split_tile(const float* __restrict__ src, u8* plane, int tid) {
#pragma unroll
    for (int r = 0; r < 16; ++r) {
        const int eidx = r * 256 + tid;
        const int row = eidx >> 6, j = eidx & 63;
        const float x = src[eidx];
        const __hip_bfloat16 h = __float2bfloat16(x);
        const float rem = x - __bfloat162float(h);
        const __hip_bfloat16 lo = __float2bfloat16(rem);
        const int pos = swzpos(row, j);
        *(__hip_bfloat16*)(plane + (size_t)pos * 2) = h;
        *(__hip_bfloat16*)(plane + 8192 + (size_t)pos * 2) = lo;
    }
}

// reconstruct 16 a-side fp32 values (lane's b row, its 16 i positions) from hi/lo planes
__device__ __forceinline__ void preload_a(const u8* plane, int b_local, int lq, int sb, float* a16) {
#pragma unroll
    for (int it = 0; it < 4; ++it) {
#pragma unroll
        for (int rg = 0; rg < 4; ++rg) {
            const int i = it * 16 + lq * 4 + rg;
            const int pos = b_local * 64 + (i ^ sb);
            const float h = __bfloat162float(*(const __hip_bfloat16*)(plane + (size_t)pos * 2));
            const float l = __bfloat162float(*(const __hip_bfloat16*)(plane + 8192 + (size_t)pos * 2));
            a16[it * 4 + rg] = h + l;
        }
    }
}

__device__ __forceinline__ void writesplit(u8* plane, int pos, float v) {
    const __hip_bfloat16 h = __float2bfloat16(v);
    const float rem = v - __bfloat162float(h);
    const __hip_bfloat16 lo = __float2bfloat16(rem);
    *(__hip_bfloat16*)(plane + (size_t)pos * 2) = h;
    *(__hip_bfloat16*)(plane + 8192 + (size_t)pos * 2) = lo;
}

// ============================ main fused pass ============================
// MODE 0: pair -> write a1/ar tiles (LDS). MODE 1: single -> write c2 tile (LDS).
// MODE 2: pair -> write global out.
template<int MODE>
__device__ __forceinline__ void run_pass(
    u8* sm, const u8* tg_hi, const u8* tg_lo,
    const short8v& Bh0, const short8v& Bl0, const short8v& Bh1, const short8v& Bl1,
    const float* aA, const float* aR,
    int w, int l, int lr, int lq, int sb, int b_local, float* outp)
{
    stage_slice(sm, tg_hi, tg_lo, 0, 0, w, l);
#pragma unroll 1
    for (int k = 0; k < 64; ++k) {
        __syncthreads();                       // drains vmcnt -> Tbuf[k&1] ready everywhere
        if (k < 63) stage_slice(sm, tg_hi, tg_lo, k + 1, (k + 1) & 1, w, l);
        const u8* tb = sm + TB(k & 1);
        float pA = 0.f, pR = 0.f;
#pragma unroll
        for (int it = 0; it < 4; ++it) {
            const int rowA = it * 16 + lr;
            const int jc0 = (lq * 8) ^ sb;
            const int jc1 = (lq * 8 + 32) ^ sb;
            const u8* rbase = tb + (size_t)rowA * 128;
            const short8v Ah0 = *(const short8v*)(rbase + jc0 * 2);
            const short8v Ah1 = *(const short8v*)(rbase + jc1 * 2);
            const short8v Al0 = *(const short8v*)(rbase + 8192 + jc0 * 2);
            const short8v Al1 = *(const short8v*)(rbase + 8192 + jc1 * 2);
            f32x4 a = {0.f, 0.f, 0.f, 0.f};
            mfma6(a, Ah0, Al0, Ah1, Al1, Bh0, Bl0, Bh1, Bl1);
#pragma unroll
            for (int rg = 0; rg < 4; ++rg) {
                pA += a[rg] * aA[it * 4 + rg];
                if (MODE != 1) pR += a[rg] * aR[it * 4 + rg];
            }
        }
        pA += __shfl_xor(pA, 16); pA += __shfl_xor(pA, 32);
        const float fA = *(const float*)(sm + FF0 + ((size_t)k * 64 + b_local) * 4);
        const float uA = tanhf(fA + pA);
        float uR = 0.f;
        if (MODE != 1) {
            pR += __shfl_xor(pR, 16); pR += __shfl_xor(pR, 32);
            const float fR = *(const float*)(sm + FF1 + ((size_t)k * 64 + b_local) * 4);
            uR = tanhf(fR + pR);
        }
        if (lq == 0) {
            const int pos = b_local * 64 + (k ^ sb);
            if (MODE == 0) {
                writesplit(sm + A1B, pos, uA);
                writesplit(sm + ARB, pos, uR);
            } else if (MODE == 1) {
                writesplit(sm + CB, pos, uA);
            } else {
                float2 v; v.x = uA; v.y = uR;
                *reinterpret_cast<float2*>(outp + (size_t)b_local * 128 + k * 2) = v;
            }
        }
    }
}

__global__ __launch_bounds__(256, 1)
void ntn_main(const float* __restrict__ e1, const float* __restrict__ p,
              const float* __restrict__ e2, const float* __restrict__ er,
              const float* __restrict__ bias, const u8* __restrict__ ws,
              float* __restrict__ out)
{
    __shared__ __align__(16) u8 sm[SMBYTES];
    const int tid = threadIdx.x;
    const int l = tid & 63;
    const int w = __builtin_amdgcn_readfirstlane(tid >> 6);
    const int lr = l & 15, lq = l >> 4;
    const int b_local = w * 16 + lr;
    const int sb = (lr & 7) << 3;
    const int blockBase = blockIdx.x * 64;

    // ---- setup: stage + split the four activation tiles ----
    split_tile(e1 + (size_t)blockBase * 64, sm + A1B, tid);
    split_tile(er + (size_t)blockBase * 64, sm + ARB, tid);
    split_tile(p  + (size_t)blockBase * 64, sm + CB,  tid);
    split_tile(e2 + (size_t)blockBase * 64, sm + E2B, tid);
    __syncthreads();

    const u16* W1h = (const u16*)(ws + WS_W);
    const u16* W1l = (const u16*)(ws + WS_W + 8192);
    const u16* W2h = (const u16*)(ws + WS_W + 16384);
    const u16* W2l = (const u16*)(ws + WS_W + 24576);

    float aA[16], aR[16];
    preload_a(sm + A1B, b_local, lq, sb, aA);   // e1 (a-side)
    preload_a(sm + ARB, b_local, lq, sb, aR);   // er

    short8v Bh0, Bl0, Bh1, Bl1;

    // ================= L1a: a1 = ntn(e1, p, T1), ar = ntn(er, p, T1) =================
    bfrags(sm + CB, b_local, lq, sb, Bh0, Bl0, Bh1, Bl1);     // p (c-side, kept for k-loop)
    {
        short8v Eh0, El0, Eh1, El1, Rh0, Rl0, Rh1, Rl1;
        bfrags(sm + A1B, b_local, lq, sb, Eh0, El0, Eh1, El1);   // e1 as B-operand for ff
        bfrags(sm + ARB, b_local, lq, sb, Rh0, Rl0, Rh1, Rl1);   // er
#pragma unroll
        for (int kt = 0; kt < 4; ++kt) {
            const int rowA = kt * 16 + lr;
            short8v h0, l0, h1, l1;
            wfrags(W2h, W2l, rowA, lq, sb, h0, l0, h1, l1);
            f32x4 s = {0.f, 0.f, 0.f, 0.f};
            mfma6(s, h0, l0, h1, l1, Bh0, Bl0, Bh1, Bl1);        // W2 . p
            wfrags(W1h, W1l, rowA, lq, sb, h0, l0, h1, l1);
            f32x4 sA = s, sR = s;
            mfma6(sA, h0, l0, h1, l1, Eh0, El0, Eh1, El1);       // + W1 . e1
            mfma6(sR, h0, l0, h1, l1, Rh0, Rl0, Rh1, Rl1);       // + W1 . er
#pragma unroll
            for (int rg = 0; rg < 4; ++rg) {
                const int kk = kt * 16 + lq * 4 + rg;
                const float bv = bias[kk];
                *(float*)(sm + FF0 + ((size_t)kk * 64 + b_local) * 4) = sA[rg] + bv;
                *(float*)(sm + FF1 + ((size_t)kk * 64 + b_local) * 4) = sR[rg] + bv;
            }
        }
    }
    run_pass<0>(sm, ws + WS_T(0), ws + WS_T(0) + WS_TLO, Bh0, Bl0, Bh1, Bl1,
                aA, aR, w, l, lr, lq, sb, b_local, nullptr);

    // ================= L1b: c2 = ntn(p, e2, T2) =================
    preload_a(sm + CB, b_local, lq, sb, aA);                  // p (a-side)
    {
        short8v Ph0, Pl0, Ph1, Pl1;
        bfrags(sm + CB, b_local, lq, sb, Ph0, Pl0, Ph1, Pl1); // p as B-operand for ff
        bfrags(sm + E2B, b_local, lq, sb, Bh0, Bl0, Bh1, Bl1);// e2 (c-side, kept)
#pragma unroll
        for (int kt = 0; kt < 4; ++kt) {
            const int rowA = kt * 16 + lr;
            short8v h0, l0, h1, l1;
            wfrags(W2h, W2l, rowA, lq, sb, h0, l0, h1, l1);
            f32x4 s = {0.f, 0.f, 0.f, 0.f};
            mfma6(s, h0, l0, h1, l1, Bh0, Bl0, Bh1, Bl1);     // W2 . e2
            wfrags(W1h, W1l, rowA, lq, sb, h0, l0, h1, l1);
            mfma6(s, h0, l0, h1, l1, Ph0, Pl0, Ph1, Pl1);     // + W1 . p
#pragma unroll
            for (int rg = 0; rg < 4; ++rg) {
                const int kk = kt * 16 + lq * 4 + rg;
                *(float*)(sm + FF0 + ((size_t)kk * 64 + b_local) * 4) = s[rg] + bias[kk];
            }
        }
    }
    run_pass<1>(sm, ws + WS_T(1), ws + WS_T(1) + WS_TLO, Bh0, Bl0, Bh1, Bl1,
                aA, aA, w, l, lr, lq, sb, b_local, nullptr);

    // ================= L2: u = ntn(a1, c2, T3), ur = ntn(ar, c2, T3) =================
    preload_a(sm + A1B, b_local, lq, sb, aA);                 // a1 (a-side)
    preload_a(sm + ARB, b_local, lq, sb, aR);                 // ar
    bfrags(sm + CB, b_local, lq, sb, Bh0, Bl0, Bh1, Bl1);     // c2 (c-side, kept)
    {
        short8v Eh0, El0, Eh1, El1, Rh0, Rl0, Rh1, Rl1;
        bfrags(sm + A1B, b_local, lq, sb, Eh0, El0, Eh1, El1);   // a1 as B-operand
        bfrags(sm + ARB, b_local, lq, sb, Rh0, Rl0, Rh1, Rl1);   // ar
#pragma unroll
        for (int kt = 0; kt < 4; ++kt) {
            const int rowA = kt * 16 + lr;
            short8v h0, l0, h1, l1;
            wfrags(W2h, W2l, rowA, lq, sb, h0, l0, h1, l1);
            f32x4 s = {0.f, 0.f, 0.f, 0.f};
            mfma6(s, h0, l0, h1, l1, Bh0, Bl0, Bh1, Bl1);        // W2 . c2
            wfrags(W1h, W1l, rowA, lq, sb, h0, l0, h1, l1);
            f32x4 sA = s, sR = s;
            mfma6(sA, h0, l0, h1, l1, Eh0, El0, Eh1, El1);       // + W1 . a1
            mfma6(sR, h0, l0, h1, l1, Rh0, Rl0, Rh1, Rl1);       // + W1 . ar
#pragma unroll
            for (int rg = 0; rg < 4; ++rg) {
                const int kk = kt * 16 + lq * 4 + rg;
                const float bv = bias[kk];
                *(float*)(sm + FF0 + ((size_t)kk * 64 + b_local) * 4) = sA[rg] + bv;
                *(float*)(sm + FF1 + ((size_t)kk * 64 + b_local) * 4) = sR[rg] + bv;
            }
        }
    }
    run_pass<2>(sm, ws + WS_T(2), ws + WS_T(2) + WS_TLO, Bh0, Bl0, Bh1, Bl1,
                aA, aR, w, l, lr, lq, sb, b_local, out + (size_t)blockBase * 128);
}

extern "C" void kernel_launch(void* const* d_in, const int* in_sizes, int n_in,
                              void* d_out, int out_size, void* d_ws, size_t ws_size,
                              hipStream_t stream) {
    const float* e1   = (const float*)d_in[0];
    const float* p    = (const float*)d_in[1];
    const float* e2   = (const float*)d_in[2];
    const float* er   = (const float*)d_in[3];
    const float* T1   = (const float*)d_in[4];
    const float* T2   = (const float*)d_in[5];
    const float* T3   = (const float*)d_in[6];
    const float* W    = (const float*)d_in[7];
    const float* bias = (const float*)d_in[8];

    u8* ws = (u8*)d_ws;
    hipLaunchKernelGGL(presplit_kernel, dim3(3104), dim3(256), 0, stream, T1, T2, T3, W, ws);
    hipLaunchKernelGGL(ntn_main, dim3(BATCH / 64), dim3(256), 0, stream,
                       e1, p, e2, er, bias, (const u8*)ws, (float*)d_out);
}

// Round 3
// 331.665 us; speedup vs baseline: 5.6294x; 1.0802x over previous
//
#include <hip/hip_runtime.h>
#include <hip/hip_bf16.h>
#include <math.h>

#define BATCH 32768

typedef __attribute__((ext_vector_type(8))) short short8v;  // 8 bf16 (MFMA A/B frag)
typedef __attribute__((ext_vector_type(4))) float f32x4;    // MFMA C/D frag
typedef unsigned short u16;
typedef unsigned char u8;

#define MFMA16 __builtin_amdgcn_mfma_f32_16x16x32_bf16

// ---- LDS map (bytes), total 67584 -> 2 blocks/CU ----
#define TBOF(buf) ((buf)*9216)   // double-buffered T slice (bf16 hi, [64 rows][pitch 144B])
#define R0OF 18432               // PRE-A (f32 [64k][64b]) -> a1 tile (hi/lo bf16) -> PRE-U
#define R1OF 34816               // PRE-R -> ar tile -> PRE-UR
#define R2OF 51200               // PRE-c2 -> c2 tile -> out-transpose member U
#define SMB  67584

// ---- d_ws map (bytes) ----
#define WS_TSTR 589824           // per tensor: 64 slices x 9216 B (bf16, row pitch 144)
#define WS_W    1769472          // W1h, W1l, W2h, W2l: 4 x 8192 (bf16 [64][64] linear)

static __device__ __forceinline__ u16 f2bf(float x) {
    __hip_bfloat16 h = __float2bfloat16(x);
    return *reinterpret_cast<u16*>(&h);
}
static __device__ __forceinline__ float bf2f(u16 v) {
    __hip_bfloat16 h = *reinterpret_cast<__hip_bfloat16*>(&v);
    return __bfloat162float(h);
}

// ============================ pre-split kernel ============================
__global__ void presplit_kernel(const float* __restrict__ T1, const float* __restrict__ T2,
                                const float* __restrict__ T3, const float* __restrict__ W,
                                u8* __restrict__ ws)
{
    const int idx = blockIdx.x * 256 + threadIdx.x;
    const int NT = 3 * 262144;
    if (idx < NT) {
        const int t = idx >> 18;
        const int r = idx & 262143;                 // k*4096 + i*64 + j
        const int k = r >> 12, i = (r >> 6) & 63, j = r & 63;
        const float* Ts = (t == 0) ? T1 : (t == 1) ? T2 : T3;
        *(u16*)(ws + (size_t)t * WS_TSTR + k * 9216 + i * 144 + j * 2) = f2bf(Ts[r]);
    } else if (idx < NT + 16384) {
        const int r = idx - NT;
        const int plane = r >> 12, k = (r >> 6) & 63, j = r & 63;
        const int half = plane >> 1, lo = plane & 1; // planes: W1h,W1l,W2h,W2l
        const float x = W[k * 128 + half * 64 + j];
        const u16 hh = f2bf(x);
        const u16 v = lo ? f2bf(x - bf2f(hh)) : hh;
        *(u16*)(ws + WS_W + (size_t)plane * 8192 + (k * 64 + j) * 2) = v;
    }
}

// ============================ device helpers ============================
__device__ __forceinline__ void stage16(const void* g, void* l) {
    __builtin_amdgcn_global_load_lds((const __attribute__((address_space(1))) unsigned int*)g,
                                     (__attribute__((address_space(3))) unsigned int*)l, 16, 0, 0);
}
// stage one 9216B T slice; waves move 2x1KB each + wave0 tail 1KB
__device__ __forceinline__ void stage_slice(u8* sm, const u8* slice, int buf, int w, int l) {
    u8* dst = sm + TBOF(buf);
    stage16(slice + w * 1024 + l * 16, dst + w * 1024);
    stage16(slice + 4096 + w * 1024 + l * 16, dst + 4096 + w * 1024);
    if (w == 0) stage16(slice + 8192 + l * 16, dst + 8192);
}

// act tile: hi plane 8KB + lo plane 8KB; [64 b][64 i] bf16, 16B-granule XOR swizzle
__device__ __forceinline__ int act_byte(int b, int i) {
    return b * 128 + ((((i >> 3) ^ b) & 7) << 4) + (i & 7) * 2;
}

struct Frag2 { short8v h, l; };
__device__ __forceinline__ Frag2 split8(const float* __restrict__ src) {
    Frag2 f;
#pragma unroll
    for (int e = 0; e < 8; ++e) {
        const float x = src[e];
        const u16 h = f2bf(x);
        f.h[e] = (short)h;
        f.l[e] = (short)f2bf(x - bf2f(h));
    }
    return f;
}
__device__ __forceinline__ Frag2 tile_frag(const u8* sm, int base, int b, int g) {
    Frag2 f;
    const int byte = base + b * 128 + (((g ^ b) & 7) << 4);
    f.h = *(const short8v*)(sm + byte);
    f.l = *(const short8v*)(sm + byte + 8192);
    return f;
}

// ============================ fused pass ============================
// MODE 0: a1/ar = ntn({e1,er}, p, T1) -> tiles in R0/R1
// MODE 1: c2 = ntn(p, e2, T2)         -> tile in R2
// MODE 2: u/ur = ntn({a1,ar}, c2, T3) -> global out
template<int MODE>
__device__ void run_pass(u8* sm, const u8* __restrict__ ws,
                         const float* __restrict__ gA, const float* __restrict__ gR,
                         const float* __restrict__ gC,
                         const float* __restrict__ bias, float* __restrict__ outg,
                         int w, int l, int lr, int lq, int blockBase, int tslot)
{
    const int tid = w * 64 + l;
    // ---------- c-side B-frags (hi+lo), kept in regs for the whole k-loop ----------
    short8v Bh[4][2], Bl[4][2];
#pragma unroll
    for (int nt = 0; nt < 4; ++nt) {
        const int b = nt * 16 + lr;
#pragma unroll
        for (int ch = 0; ch < 2; ++ch) {
            Frag2 f;
            if (MODE < 2) f = split8(gC + (size_t)(blockBase + b) * 64 + ch * 32 + lq * 8);
            else          f = tile_frag(sm, R2OF, b, ch * 4 + lq);
            Bh[nt][ch] = f.h; Bl[nt][ch] = f.l;
        }
    }
    // ---------- a-side scalars (lane's 4 b x 4 i) ----------
    float aA[16], aR[16];
#pragma unroll
    for (int nt = 0; nt < 4; ++nt) {
        const int b = nt * 16 + lr;
#pragma unroll
        for (int rg = 0; rg < 4; ++rg) {
            const int i = w * 16 + lq * 4 + rg;
            if (MODE < 2) {
                aA[nt*4+rg] = gA[(size_t)(blockBase + b) * 64 + i];
                if (MODE == 0) aR[nt*4+rg] = gR[(size_t)(blockBase + b) * 64 + i];
            } else {
                const int byA = R0OF + act_byte(b, i);
                aA[nt*4+rg] = bf2f(*(const u16*)(sm + byA)) + bf2f(*(const u16*)(sm + byA + 8192));
                const int byR = R1OF + act_byte(b, i);
                aR[nt*4+rg] = bf2f(*(const u16*)(sm + byR)) + bf2f(*(const u16*)(sm + byR + 8192));
            }
        }
    }
    // ---------- MODE2: a-side hi frags for ff (must read R0/R1 before overwrite) ----------
    short8v FA2[4][2], FR2[4][2];
    if (MODE == 2) {
#pragma unroll
        for (int nt = 0; nt < 4; ++nt) {
#pragma unroll
            for (int ch = 0; ch < 2; ++ch) {
                FA2[nt][ch] = tile_frag(sm, R0OF, nt * 16 + lr, ch * 4 + lq).h;
                FR2[nt][ch] = tile_frag(sm, R1OF, nt * 16 + lr, ch * 4 + lq).h;
            }
        }
        __syncthreads();   // all R0/R1/R2 reads done; safe to overwrite with PRE
    }
    // ---------- ff prologue via MFMA: PRE[k][b] = W1.a + W2.c + bias ----------
    float* PA = (float*)(sm + (MODE == 1 ? R2OF : R0OF));
    float* PR = (float*)(sm + R1OF);
    {
        const u16* W1h = (const u16*)(ws + WS_W);
        const u16* W1l = (const u16*)(ws + WS_W + 8192);
        const u16* W2h = (const u16*)(ws + WS_W + 16384);
        const u16* W2l = (const u16*)(ws + WS_W + 24576);
        const int krow = w * 16 + lr;
        short8v w1h[2], w1l[2], w2h[2], w2l[2];
#pragma unroll
        for (int ch = 0; ch < 2; ++ch) {
            const int off = krow * 64 + ch * 32 + lq * 8;
            w1h[ch] = *(const short8v*)(W1h + off);
            w1l[ch] = *(const short8v*)(W1l + off);
            w2h[ch] = *(const short8v*)(W2h + off);
            w2l[ch] = *(const short8v*)(W2l + off);
        }
        float bv[4];
#pragma unroll
        for (int rg = 0; rg < 4; ++rg) bv[rg] = bias[w * 16 + lq * 4 + rg];
#pragma unroll
        for (int nt = 0; nt < 4; ++nt) {
            const int b = nt * 16 + lr;
            f32x4 s = {0.f,0.f,0.f,0.f};
#pragma unroll
            for (int ch = 0; ch < 2; ++ch) {          // W2 . c (3-way split)
                s = MFMA16(w2h[ch], Bh[nt][ch], s, 0,0,0);
                s = MFMA16(w2h[ch], Bl[nt][ch], s, 0,0,0);
                s = MFMA16(w2l[ch], Bh[nt][ch], s, 0,0,0);
            }
            f32x4 sA = s, sR = s;
#pragma unroll
            for (int ch = 0; ch < 2; ++ch) {          // + W1 . a
                Frag2 fa;
                if (MODE < 2) fa = split8(gA + (size_t)(blockBase + b) * 64 + ch * 32 + lq * 8);
                else { fa.h = FA2[nt][ch]; fa.l = FA2[nt][ch]; }
                sA = MFMA16(w1h[ch], fa.h, sA, 0,0,0);
                if (MODE < 2) sA = MFMA16(w1h[ch], fa.l, sA, 0,0,0);
                sA = MFMA16(w1l[ch], fa.h, sA, 0,0,0);
            }
            if (MODE != 1) {
#pragma unroll
                for (int ch = 0; ch < 2; ++ch) {
                    Frag2 fr;
                    if (MODE == 0) fr = split8(gR + (size_t)(blockBase + b) * 64 + ch * 32 + lq * 8);
                    else { fr.h = FR2[nt][ch]; fr.l = FR2[nt][ch]; }
                    sR = MFMA16(w1h[ch], fr.h, sR, 0,0,0);
                    if (MODE == 0) sR = MFMA16(w1h[ch], fr.l, sR, 0,0,0);
                    sR = MFMA16(w1l[ch], fr.h, sR, 0,0,0);
                }
            }
#pragma unroll
            for (int rg = 0; rg < 4; ++rg) {
                const int k = w * 16 + lq * 4 + rg;
                PA[k * 64 + b] = sA[rg] + bv[rg];
                if (MODE != 1) PR[k * 64 + b] = sR[rg] + bv[rg];
            }
        }
    }
    // ---------- k-loop: waves partition i (M); one ds_add per member per step ----------
    const u8* tsrc = ws + (size_t)tslot * WS_TSTR;
    stage_slice(sm, tsrc, 0, w, l);
    const int bit0 = lq & 1, bit1 = lq & 2;
#pragma unroll 1
    for (int k = 0; k < 64; ++k) {
        __syncthreads();                              // slice k staged; PRE visible
        if (k < 63) stage_slice(sm, tsrc + (size_t)(k + 1) * 9216, (k + 1) & 1, w, l);
        const u8* tb = sm + TBOF(k & 1) + (w * 16 + lr) * 144 + lq * 16;
        const short8v Ah0 = *(const short8v*)tb;          // T rows, j 0..31
        const short8v Ah1 = *(const short8v*)(tb + 64);   // j 32..63
        float pa[4], pr[4];
#pragma unroll
        for (int nt = 0; nt < 4; ++nt) {
            f32x4 a = {0.f,0.f,0.f,0.f};
            a = MFMA16(Ah0, Bh[nt][0], a, 0,0,0);
            a = MFMA16(Ah0, Bl[nt][0], a, 0,0,0);
            a = MFMA16(Ah1, Bh[nt][1], a, 0,0,0);
            a = MFMA16(Ah1, Bl[nt][1], a, 0,0,0);
            pa[nt] = a[0]*aA[nt*4] + a[1]*aA[nt*4+1] + a[2]*aA[nt*4+2] + a[3]*aA[nt*4+3];
            if (MODE != 1)
                pr[nt] = a[0]*aR[nt*4] + a[1]*aR[nt*4+1] + a[2]*aR[nt*4+2] + a[3]*aR[nt*4+3];
        }
        {   // transpose-reduce over lq: lane ends with full partial for nt == lq, b == l
            float t0 = bit0 ? pa[0] : pa[1];
            float t1 = bit0 ? pa[2] : pa[3];
            float g0 = __shfl_xor(t0, 16);
            float g1 = __shfl_xor(t1, 16);
            float m0 = (bit0 ? pa[1] : pa[0]) + g0;
            float m1 = (bit0 ? pa[3] : pa[2]) + g1;
            float t2 = bit1 ? m0 : m1;
            float g2 = __shfl_xor(t2, 32);
            float fin = (bit1 ? m1 : m0) + g2;
            atomicAdd(&PA[k * 64 + l], fin);
        }
        if (MODE != 1) {
            float t0 = bit0 ? pr[0] : pr[1];
            float t1 = bit0 ? pr[2] : pr[3];
            float g0 = __shfl_xor(t0, 16);
            float g1 = __shfl_xor(t1, 16);
            float m0 = (bit0 ? pr[1] : pr[0]) + g0;
            float m1 = (bit0 ? pr[3] : pr[2]) + g1;
            float t2 = bit1 ? m0 : m1;
            float g2 = __shfl_xor(t2, 32);
            float fin = (bit1 ? m1 : m0) + g2;
            atomicAdd(&PR[k * 64 + l], fin);
        }
    }
    __syncthreads();
    // ---------- epilogue: batched tanh ----------
    if (MODE < 2) {
        float va[16], vr[16];
#pragma unroll
        for (int r = 0; r < 16; ++r) {
            const int idx = r * 256 + tid;
            const int k = idx >> 6, b = idx & 63;
            va[r] = PA[k * 64 + b];
            if (MODE == 0) vr[r] = PR[k * 64 + b];
        }
        __syncthreads();                              // all PRE reads before tile overwrite
        const int tbase = (MODE == 1) ? R2OF : R0OF;
#pragma unroll
        for (int r = 0; r < 16; ++r) {
            const int idx = r * 256 + tid;
            const int k = idx >> 6, b = idx & 63;
            const int by = act_byte(b, k);
            const float u = tanhf(va[r]);
            const u16 h = f2bf(u);
            *(u16*)(sm + tbase + by) = h;
            *(u16*)(sm + tbase + 8192 + by) = f2bf(u - bf2f(h));
            if (MODE == 0) {
                const float u2 = tanhf(vr[r]);
                const u16 h2 = f2bf(u2);
                *(u16*)(sm + R1OF + by) = h2;
                *(u16*)(sm + R1OF + 8192 + by) = f2bf(u2 - bf2f(h2));
            }
        }
        __syncthreads();
    } else {
        float vu[16], vr2[16];
#pragma unroll
        for (int r = 0; r < 16; ++r) {
            const int idx = r * 256 + tid;
            const int k = idx >> 6, b = idx & 63;
            vu[r] = PA[k * 64 + b];
            vr2[r] = PR[k * 64 + b];
        }
        __syncthreads();
        float* TU = (float*)(sm + R2OF);              // c2 frags already consumed
        float* TR = (float*)(sm + TBOF(0));           // T staging done
#pragma unroll
        for (int r = 0; r < 16; ++r) {
            const int idx = r * 256 + tid;
            const int k = idx >> 6, b = idx & 63;
            TU[b * 64 + (k ^ b)] = tanhf(vu[r]);      // XOR-swizzled transpose, conflict-free
            TR[b * 64 + (k ^ b)] = tanhf(vr2[r]);
        }
        __syncthreads();
#pragma unroll
        for (int r = 0; r < 16; ++r) {
            const int idx = r * 256 + tid;
            const int b = idx >> 6, k = idx & 63;
            float2 o;
            o.x = TU[b * 64 + (k ^ b)];
            o.y = TR[b * 64 + (k ^ b)];
            *(float2*)(outg + ((size_t)(blockBase + b) * 64 + k) * 2) = o;  // coalesced
        }
    }
}

__global__ __launch_bounds__(256, 2)
void ntn_main(const float* __restrict__ e1, const float* __restrict__ p,
              const float* __restrict__ e2, const float* __restrict__ er,
              const float* __restrict__ bias, const u8* __restrict__ ws,
              float* __restrict__ out)
{
    __shared__ __align__(16) u8 sm[SMB];
    const int tid = threadIdx.x;
    const int l = tid & 63;
    const int w = __builtin_amdgcn_readfirstlane(tid >> 6);
    const int lr = l & 15, lq = l >> 4;
    const int blockBase = blockIdx.x * 64;

    run_pass<0>(sm, ws, e1, er, p, bias, nullptr, w, l, lr, lq, blockBase, 0);
    run_pass<1>(sm, ws, p, nullptr, e2, bias, nullptr, w, l, lr, lq, blockBase, 1);
    run_pass<2>(sm, ws, nullptr, nullptr, nullptr, bias, out, w, l, lr, lq, blockBase, 2);
}

extern "C" void kernel_launch(void* const* d_in, const int* in_sizes, int n_in,
                              void* d_out, int out_size, void* d_ws, size_t ws_size,
                              hipStream_t stream) {
    const float* e1   = (const float*)d_in[0];
    const float* p    = (const float*)d_in[1];
    const float* e2   = (const float*)d_in[2];
    const float* er   = (const float*)d_in[3];
    const float* T1   = (const float*)d_in[4];
    const float* T2   = (const float*)d_in[5];
    const float* T3   = (const float*)d_in[6];
    const float* W    = (const float*)d_in[7];
    const float* bias = (const float*)d_in[8];

    u8* ws = (u8*)d_ws;
    hipLaunchKernelGGL(presplit_kernel, dim3(3136), dim3(256), 0, stream, T1, T2, T3, W, ws);
    hipLaunchKernelGGL(ntn_main, dim3(BATCH / 64), dim3(256), 0, stream,
                       e1, p, e2, er, bias, (const u8*)ws, (float*)d_out);
}

// Round 4
// 223.837 us; speedup vs baseline: 8.3413x; 1.4817x over previous
//
#include <hip/hip_runtime.h>
#include <hip/hip_bf16.h>
#include <math.h>

#define BATCH 32768

typedef __attribute__((ext_vector_type(8))) short short8v;  // 8 bf16 (MFMA A/B frag)
typedef __attribute__((ext_vector_type(4))) float f32x4;    // MFMA C/D frag
typedef unsigned short u16;
typedef unsigned char u8;

#define MFMA16 __builtin_amdgcn_mfma_f32_16x16x32_bf16

// ---- LDS map (bytes), total 81920 -> exactly 2 blocks/CU (160 KiB) ----
// [0,32768): T stage bufs, 2 x [4 kt][2 plane][2048]
#define TILE_P  32768   // pass A c-tile f32 [j][64] -> a1 tile (bf16 hi 8K | lo 8K)
#define TILE_AR 49152   // ar tile (bf16 hi | lo)
#define TILE_E2 65536   // e2 f32 [j][b] -> c2 f32 [j][b]
#define SMB     81920
// final output transpose area: offset 0, pitch 520 B per b-row (33280 B, over dead T bufs + a1)

// ---- d_ws map ----
// per tensor t: 1 MiB at t*1048576: [j 64][kt 4][plane 2][krow 16][i-chunks swizzled 8][8 bf16]
#define WS_W    3145728  // W1h, W1l, W2h, W2l: 4 x 8192 B (bf16 [k][64] linear)

static __device__ __forceinline__ u16 f2bf(float x) {
    __hip_bfloat16 h = __float2bfloat16(x);
    return *reinterpret_cast<u16*>(&h);
}
static __device__ __forceinline__ float bf2f(u16 v) {
    __hip_bfloat16 h = *reinterpret_cast<__hip_bfloat16*>(&v);
    return __bfloat162float(h);
}

// ============================ pre-split kernel ============================
// T tensors -> j-sliced, kt-blocked, XOR-swizzled bf16 hi/lo planes. W -> 4 linear planes.
__global__ void presplit_kernel(const float* __restrict__ T1, const float* __restrict__ T2,
                                const float* __restrict__ T3, const float* __restrict__ W,
                                u8* __restrict__ ws)
{
    const int idx = blockIdx.x * 256 + threadIdx.x;
    const int NT = 3 * 262144;
    if (idx < NT) {
        const int t = idx >> 18;
        const int r = idx & 262143;                 // k*4096 + i*64 + j
        const int k = r >> 12, i = (r >> 6) & 63, j = r & 63;
        const float* Ts = (t == 0) ? T1 : (t == 1) ? T2 : T3;
        const float x = Ts[r];
        const u16 h = f2bf(x);
        const u16 lo = f2bf(x - bf2f(h));
        const size_t base = (size_t)t * 1048576 + j * 16384 + (k >> 4) * 4096
                          + (k & 15) * 128 + (((i >> 3) ^ (k & 7)) << 4) + (i & 7) * 2;
        *(u16*)(ws + base) = h;            // hi plane
        *(u16*)(ws + base + 2048) = lo;    // lo plane
    } else if (idx < NT + 16384) {
        const int r = idx - NT;
        const int plane = r >> 12, k = (r >> 6) & 63, j = r & 63; // W1h,W1l,W2h,W2l
        const int half = plane >> 1, lo = plane & 1;
        const float x = W[k * 128 + half * 64 + j];
        const u16 hh = f2bf(x);
        const u16 v = lo ? f2bf(x - bf2f(hh)) : hh;
        *(u16*)(ws + WS_W + (size_t)plane * 8192 + (k * 64 + j) * 2) = v;
    }
}

// ============================ device helpers ============================
__device__ __forceinline__ void stage16(const void* g, void* l) {
    __builtin_amdgcn_global_load_lds((const __attribute__((address_space(1))) unsigned int*)g,
                                     (__attribute__((address_space(3))) unsigned int*)l, 16, 0, 0);
}
// stage this wave's 2KB plane chunk of one slice (2 x 1KB)
__device__ __forceinline__ void stage2(u8* sm, const u8* src, int buf, int kt, int pl, int l) {
    u8* dst = sm + buf * 16384 + kt * 4096 + pl * 2048;
    stage16(src + l * 16, dst);
    stage16(src + 1024 + l * 16, dst + 1024);
}

struct Frag2 { short8v h, l; };
// split 8 consecutive f32 into bf16 hi/lo fragments
__device__ __forceinline__ Frag2 split8(const float* __restrict__ src) {
    Frag2 f;
#pragma unroll
    for (int e = 0; e < 8; ++e) {
        const float x = src[e];
        const u16 h = f2bf(x);
        f.h[e] = (short)h;
        f.l[e] = (short)f2bf(x - bf2f(h));
    }
    return f;
}

// ============================ fused pass ============================
// S-form: per j-step, S_j[k,b] = sum_i T[k,i,j] a[b,i] via MFMA (a-frags static),
// then bil[k,b] += c[b,j] * S_j[k,b] (per-lane FMA into resident accumulator).
// MODE 0: {a1,ar} = ntn({e1,er}, p, T1)  waves = (kt, variant). -> a1/ar LDS tiles
// MODE 1: c2 = ntn(p, e2, T2)            waves = (kt, b-half).  -> c2 f32 LDS tile
// MODE 2: {u,ur} = ntn({a1,ar}, c2, T3)  waves = (kt, variant). -> global out
template<int MODE>
__device__ void pass_run(u8* sm, const u8* __restrict__ ws,
                         const float* __restrict__ gA0, const float* __restrict__ gA1,
                         const float* __restrict__ gC,
                         const float* __restrict__ bias, float* __restrict__ outg,
                         int B0, int tid)
{
    const int l  = tid & 63;
    const int w8 = __builtin_amdgcn_readfirstlane(tid >> 6);
    const int kt = w8 & 3, hi8 = w8 >> 2;
    const int lr = l & 15, lq = l >> 4;
    constexpr int NT = (MODE == 1) ? 2 : 4;
    const int boff = (MODE == 1) ? hi8 * 32 : 0;
    const int ctile = (MODE == 0) ? TILE_P : TILE_E2;

    float bv[4];
#pragma unroll
    for (int rg = 0; rg < 4; ++rg) bv[rg] = bias[kt * 16 + lq * 4 + rg];

    // ---------- a-side B-frags (static for the whole j-loop) ----------
    short8v ah[NT][2], al[NT][2];
#pragma unroll
    for (int nt = 0; nt < NT; ++nt) {
        const int b = boff + nt * 16 + lr;
#pragma unroll
        for (int ih = 0; ih < 2; ++ih) {
            if (MODE < 2) {
                const float* src = (MODE == 0 && hi8) ? gA1 : gA0;
                Frag2 f = split8(src + (size_t)(B0 + b) * 64 + ih * 32 + lq * 8);
                ah[nt][ih] = f.h; al[nt][ih] = f.l;
            } else {
                const int tb = hi8 ? TILE_AR : TILE_P;
                const int by = tb + b * 128 + (((ih * 4 + lq) ^ (b & 7)) << 4);
                ah[nt][ih] = *(const short8v*)(sm + by);
                al[nt][ih] = *(const short8v*)(sm + by + 8192);
            }
        }
    }

    // ---------- accumulator init: ff = W1.a + W2.c via MFMA ----------
    f32x4 bil[NT];
#pragma unroll
    for (int nt = 0; nt < NT; ++nt) bil[nt] = (f32x4){0.f, 0.f, 0.f, 0.f};
    {
        const u16* Wb = (const u16*)(ws + WS_W);
#pragma unroll
        for (int fh = 0; fh < 2; ++fh) {
            const int woff = (kt * 16 + lr) * 64 + fh * 32 + lq * 8;
            const short8v w1h = *(const short8v*)(Wb + woff);
            const short8v w1l = *(const short8v*)(Wb + 4096 + woff);
            const short8v w2h = *(const short8v*)(Wb + 8192 + woff);
            const short8v w2l = *(const short8v*)(Wb + 12288 + woff);
#pragma unroll
            for (int nt = 0; nt < NT; ++nt) {
                const int b = boff + nt * 16 + lr;
                Frag2 fc;
                if (MODE < 2) {
                    fc = split8(gC + (size_t)(B0 + b) * 64 + fh * 32 + lq * 8);
                } else {
                    float tmp[8];
#pragma unroll
                    for (int e = 0; e < 8; ++e)
                        tmp[e] = *(const float*)(sm + TILE_E2 + (((fh * 32 + lq * 8 + e) * 64) + b) * 4);
                    fc = split8(tmp);
                }
                bil[nt] = MFMA16(w2h, fc.h, bil[nt], 0, 0, 0);
                bil[nt] = MFMA16(w2h, fc.l, bil[nt], 0, 0, 0);
                bil[nt] = MFMA16(w2l, fc.h, bil[nt], 0, 0, 0);
                bil[nt] = MFMA16(w1h, ah[nt][fh], bil[nt], 0, 0, 0);
                bil[nt] = MFMA16(w1h, al[nt][fh], bil[nt], 0, 0, 0);
                bil[nt] = MFMA16(w1l, ah[nt][fh], bil[nt], 0, 0, 0);
            }
        }
    }

    // ---------- j-loop: wave-private staging, raw barriers, counted vmcnt ----------
    const u8* tsrc = ws + (size_t)MODE * 1048576 + kt * 4096 + hi8 * 2048;
    const int c0 = ((lq) ^ (lr & 7)) << 4;        // swizzled chunk offsets for A-frags
    const int c1 = ((4 + lq) ^ (lr & 7)) << 4;
    asm volatile("s_waitcnt vmcnt(0)" ::: "memory");
    stage2(sm, tsrc, 0, kt, hi8, l);              // slice 0
#pragma unroll 1
    for (int j = 0; j < 64; ++j) {
        asm volatile("s_waitcnt vmcnt(0)" ::: "memory");   // own slice-j loads landed
        __builtin_amdgcn_sched_barrier(0);
        __builtin_amdgcn_s_barrier();                       // partner's plane landed too
        __builtin_amdgcn_sched_barrier(0);
        if (j < 63) stage2(sm, tsrc + (size_t)(j + 1) * 16384, (j + 1) & 1, kt, hi8, l);
        const u8* tb = sm + (j & 1) * 16384 + kt * 4096 + lr * 128;
        const short8v Th0 = *(const short8v*)(tb + c0);
        const short8v Th1 = *(const short8v*)(tb + c1);
        const short8v Tl0 = *(const short8v*)(tb + 2048 + c0);
        const short8v Tl1 = *(const short8v*)(tb + 2048 + c1);
#pragma unroll
        for (int nt = 0; nt < NT; ++nt) {
            const int b = boff + nt * 16 + lr;
            const float cs = *(const float*)(sm + ctile + (j * 64 + b) * 4);
            f32x4 S = (f32x4){0.f, 0.f, 0.f, 0.f};
            S = MFMA16(Th0, ah[nt][0], S, 0, 0, 0);
            S = MFMA16(Th0, al[nt][0], S, 0, 0, 0);
            S = MFMA16(Tl0, ah[nt][0], S, 0, 0, 0);
            S = MFMA16(Th1, ah[nt][1], S, 0, 0, 0);
            S = MFMA16(Th1, al[nt][1], S, 0, 0, 0);
            S = MFMA16(Tl1, ah[nt][1], S, 0, 0, 0);
            bil[nt][0] += cs * S[0];
            bil[nt][1] += cs * S[1];
            bil[nt][2] += cs * S[2];
            bil[nt][3] += cs * S[3];
        }
    }

    // ---------- epilogue ----------
    if (MODE == 0) {
        __syncthreads();                          // everyone done reading p-tile
        const int tb = hi8 ? TILE_AR : TILE_P;
#pragma unroll
        for (int nt = 0; nt < 4; ++nt) {
#pragma unroll
            for (int rg = 0; rg < 4; ++rg) {
                const float u = tanhf(bil[nt][rg] + bv[rg]);
                const int k = kt * 16 + lq * 4 + rg, b = nt * 16 + lr;
                const int by = b * 128 + (((k >> 3) ^ (b & 7)) << 4) + (k & 7) * 2;
                const u16 h = f2bf(u);
                *(u16*)(sm + tb + by) = h;
                *(u16*)(sm + tb + 8192 + by) = f2bf(u - bf2f(h));
            }
        }
    } else if (MODE == 1) {
        __syncthreads();                          // everyone done reading e2-tile
#pragma unroll
        for (int nt = 0; nt < 2; ++nt) {
#pragma unroll
            for (int rg = 0; rg < 4; ++rg) {
                const float u = tanhf(bil[nt][rg] + bv[rg]);
                const int jj = kt * 16 + lq * 4 + rg, b = hi8 * 32 + nt * 16 + lr;
                *(float*)(sm + TILE_E2 + (jj * 64 + b) * 4) = u;
            }
        }
        __syncthreads();                          // c2 + a1/ar tiles ready for pass C
    } else {
        __syncthreads();                          // all waves done with T bufs / a1 tile
#pragma unroll
        for (int nt = 0; nt < 4; ++nt) {
#pragma unroll
            for (int rg = 0; rg < 4; ++rg) {
                const float u = tanhf(bil[nt][rg] + bv[rg]);
                const int k = kt * 16 + lq * 4 + rg, b = nt * 16 + lr;
                *(float*)(sm + b * 520 + k * 8 + hi8 * 4) = u;   // [b][k][(u,ur)] padded
            }
        }
        __syncthreads();
#pragma unroll
        for (int r = 0; r < 8; ++r) {             // coalesced store
            const int idx = r * 512 + tid;
            const int b = idx >> 6, q = idx & 63;
            const float2 o = *(const float2*)(sm + b * 520 + q * 8);
            *(float2*)(outg + (size_t)(B0 + b) * 128 + q * 2) = o;
        }
    }
}

__global__ __launch_bounds__(512, 4)
void ntn_main(const float* __restrict__ e1, const float* __restrict__ p,
              const float* __restrict__ e2, const float* __restrict__ er,
              const float* __restrict__ bias, const u8* __restrict__ ws,
              float* __restrict__ out)
{
    __shared__ __align__(16) u8 sm[SMB];
    const int tid = threadIdx.x;
    const int B0 = blockIdx.x * 64;

    // fill c-tiles: p and e2 as f32 [j][b] (transposed)
#pragma unroll
    for (int r = 0; r < 8; ++r) {
        const int idx = r * 512 + tid;
        const int b = idx >> 6, j = idx & 63;
        ((float*)(sm + TILE_P))[j * 64 + b]  = p[(size_t)(B0 + b) * 64 + j];
        ((float*)(sm + TILE_E2))[j * 64 + b] = e2[(size_t)(B0 + b) * 64 + j];
    }
    __syncthreads();

    pass_run<0>(sm, ws, e1, er, p, bias, nullptr, B0, tid);
    pass_run<1>(sm, ws, p, nullptr, e2, bias, nullptr, B0, tid);
    pass_run<2>(sm, ws, nullptr, nullptr, nullptr, bias, out, B0, tid);
}

extern "C" void kernel_launch(void* const* d_in, const int* in_sizes, int n_in,
                              void* d_out, int out_size, void* d_ws, size_t ws_size,
                              hipStream_t stream) {
    const float* e1   = (const float*)d_in[0];
    const float* p    = (const float*)d_in[1];
    const float* e2   = (const float*)d_in[2];
    const float* er   = (const float*)d_in[3];
    const float* T1   = (const float*)d_in[4];
    const float* T2   = (const float*)d_in[5];
    const float* T3   = (const float*)d_in[6];
    const float* W    = (const float*)d_in[7];
    const float* bias = (const float*)d_in[8];

    u8* ws = (u8*)d_ws;
    hipLaunchKernelGGL(presplit_kernel, dim3(3136), dim3(256), 0, stream, T1, T2, T3, W, ws);
    hipLaunchKernelGGL(ntn_main, dim3(BATCH / 64), dim3(512), 0, stream,
                       e1, p, e2, er, bias, (const u8*)ws, (float*)d_out);
}

// Round 5
// 194.799 us; speedup vs baseline: 9.5847x; 1.1491x over previous
//
#include <hip/hip_runtime.h>
#include <hip/hip_bf16.h>
#include <math.h>

#define BATCH 32768

typedef __attribute__((ext_vector_type(8))) short short8v;  // 8 bf16 (MFMA A/B frag)
typedef __attribute__((ext_vector_type(4))) float f32x4;    // MFMA C/D frag
typedef unsigned short u16;
typedef unsigned char u8;

#define MFMA16 __builtin_amdgcn_mfma_f32_16x16x32_bf16

// ---- LDS map (bytes), 80 KiB exactly -> 2 blocks/CU ----
// f32 [64 feat][64 b] tiles, XOR-swizzled: elem (f, b) at [f*64 + (b ^ (f & 31))]
#define TILE_A 0        // e1^T -> a1^T -> out-U staging ([b][k^(b&31)])
#define TILE_B 16384    // er^T -> ar^T -> out-UR staging
#define TILE_C 32768    // p^T  -> c2^T
#define PRE    49152    // [2 var][64 k][64 b] f32, i-half merge scratch (32 KiB)
#define SMB    81920

// ---- d_ws map ----
// T tensor t at t*1MiB, frag-ready: [i 64][kt 4][jh 2][plane hi/lo][klo 16][lq 4][16B]
//   byte = t*1MB + i*16384 + kt*4096 + jh*2048 + plane*1024 + klo*64 + lq*16
#define WS_W 3145728    // W planes: W1h, W1l, W2h, W2l, each 8192 B bf16 [k][64] linear

static __device__ __forceinline__ u16 f2bf(float x) {
    __hip_bfloat16 h = __float2bfloat16(x);
    return *reinterpret_cast<u16*>(&h);
}
static __device__ __forceinline__ float bf2f(u16 v) {
    __hip_bfloat16 h = *reinterpret_cast<__hip_bfloat16*>(&v);
    return __bfloat162float(h);
}

// ============================ pre-split kernel ============================
__global__ void presplit_kernel(const float* __restrict__ T1, const float* __restrict__ T2,
                                const float* __restrict__ T3, const float* __restrict__ W,
                                u8* __restrict__ ws)
{
    const int idx = blockIdx.x * 256 + threadIdx.x;
    const int NT = 3 * 262144;
    if (idx < NT) {
        const int t = idx >> 18;
        const int r = idx & 262143;                  // k*4096 + i*64 + j
        const int k = r >> 12, i = (r >> 6) & 63, j = r & 63;
        const float* Ts = (t == 0) ? T1 : (t == 1) ? T2 : T3;
        const float x = Ts[r];
        const u16 h = f2bf(x);
        const u16 lo = f2bf(x - bf2f(h));
        const size_t base = (size_t)t * 1048576 + (size_t)i * 16384 + (k >> 4) * 4096
                          + (j >> 5) * 2048 + (k & 15) * 64 + ((j >> 3) & 3) * 16 + (j & 7) * 2;
        *(u16*)(ws + base) = h;             // hi plane
        *(u16*)(ws + base + 1024) = lo;     // lo plane
    } else if (idx < NT + 16384) {
        const int r = idx - NT;
        const int plane = r >> 12, k = (r >> 6) & 63, j = r & 63; // W1h,W1l,W2h,W2l
        const int half = plane >> 1, lo = plane & 1;
        const float x = W[k * 128 + half * 64 + j];
        const u16 hh = f2bf(x);
        const u16 v = lo ? f2bf(x - bf2f(hh)) : hh;
        *(u16*)(ws + WS_W + (size_t)plane * 8192 + (k * 64 + j) * 2) = v;
    }
}

// ============================ device helpers ============================
struct Frag2 { short8v h, l; };
__device__ __forceinline__ Frag2 split8(const float* __restrict__ src) {
    Frag2 f;
#pragma unroll
    for (int e = 0; e < 8; ++e) {
        const float x = src[e];
        const u16 h = f2bf(x);
        f.h[e] = (short)h;
        f.l[e] = (short)f2bf(x - bf2f(h));
    }
    return f;
}

// ============================ fused pass ============================
// Shared-S form: per i-step, S'_i[k,b] = sum_j T[k,i,j] c[b,j] via MFMA (c shared across
// pair members, static frags); then bil_v[k,b] += a_v[b,i] * S'_i (exact f32 scalars).
// Waves = (kt 4) x (ih 2); i-halves merged once per pass through PRE.
// MODE 0: {a1,ar} = ntn({e1,er}, p, T1) -> tiles A/B
// MODE 1: c2 = ntn(p, e2, T2)           -> tile C
// MODE 2: {u,ur} = ntn({a1,ar}, c2, T3) -> global out
template<int MODE>
__device__ void pass_run(u8* sm, const u8* __restrict__ ws,
                         const float* __restrict__ gC,   // shared c-side rows (MODE<2)
                         const float* __restrict__ gF0,  // a-side rows for ff (MODE<2)
                         const float* __restrict__ gF1,
                         const float* __restrict__ bias, float* __restrict__ outg,
                         int B0, int kt, int jh, int lr, int lq, int tid)
{
    constexpr int NV = (MODE == 1) ? 1 : 2;
    const int SA = (MODE == 1) ? TILE_C : TILE_A;   // per-i scalar tile, variant 0

    __syncthreads();   // prior pass's tile writes visible; PRE reusable

    // ---------- shared c-side B-frags (static for whole i-loop) ----------
    short8v Bh[4][2], Bl[4][2];
#pragma unroll
    for (int nt = 0; nt < 4; ++nt) {
        const int b = nt * 16 + lr;
#pragma unroll
        for (int h = 0; h < 2; ++h) {
            Frag2 f;
            if (MODE < 2) {
                f = split8(gC + (size_t)(B0 + b) * 64 + h * 32 + lq * 8);
            } else {
                float tmp[8];
#pragma unroll
                for (int e = 0; e < 8; ++e) {
                    const int j = h * 32 + lq * 8 + e;
                    tmp[e] = ((const float*)(sm + TILE_C))[j * 64 + (b ^ (j & 31))];
                }
                f = split8(tmp);
            }
            Bh[nt][h] = f.h; Bl[nt][h] = f.l;
        }
    }

    // ---------- bil init: ih=0 waves carry ff+bias, ih=1 start at 0 ----------
    f32x4 bil[NV][4];
#pragma unroll
    for (int v = 0; v < NV; ++v)
#pragma unroll
    for (int nt = 0; nt < 4; ++nt) bil[v][nt] = (f32x4){0.f, 0.f, 0.f, 0.f};

    if (jh == 0) {
        const u16* Wp = (const u16*)(ws + WS_W);
        short8v w1h[2], w1l[2], w2h[2], w2l[2];
#pragma unroll
        for (int h = 0; h < 2; ++h) {
            const int off = (kt * 16 + lr) * 64 + h * 32 + lq * 8;
            w1h[h] = *(const short8v*)(Wp + off);
            w1l[h] = *(const short8v*)(Wp + 4096 + off);
            w2h[h] = *(const short8v*)(Wp + 8192 + off);
            w2l[h] = *(const short8v*)(Wp + 12288 + off);
        }
        float bv[4];
#pragma unroll
        for (int rg = 0; rg < 4; ++rg) bv[rg] = bias[kt * 16 + lq * 4 + rg];
#pragma unroll
        for (int nt = 0; nt < 4; ++nt) {
            const int b = nt * 16 + lr;
            f32x4 s = {0.f, 0.f, 0.f, 0.f};
#pragma unroll
            for (int h = 0; h < 2; ++h) {            // W2 . c (3-way split)
                s = MFMA16(w2h[h], Bh[nt][h], s, 0, 0, 0);
                s = MFMA16(w2h[h], Bl[nt][h], s, 0, 0, 0);
                s = MFMA16(w2l[h], Bh[nt][h], s, 0, 0, 0);
            }
#pragma unroll
            for (int v = 0; v < NV; ++v) {
                f32x4 sv = s;
#pragma unroll
                for (int h = 0; h < 2; ++h) {        // + W1 . a_v
                    Frag2 fa;
                    if (MODE < 2) {
                        const float* g = (v == 0) ? gF0 : gF1;
                        fa = split8(g + (size_t)(B0 + b) * 64 + h * 32 + lq * 8);
                    } else {
                        float tmp[8];
#pragma unroll
                        for (int e = 0; e < 8; ++e) {
                            const int j = h * 32 + lq * 8 + e;
                            tmp[e] = ((const float*)(sm + (v ? TILE_B : TILE_A)))[j * 64 + (b ^ (j & 31))];
                        }
                        fa = split8(tmp);
                    }
                    sv = MFMA16(w1h[h], fa.h, sv, 0, 0, 0);
                    sv = MFMA16(w1h[h], fa.l, sv, 0, 0, 0);
                    sv = MFMA16(w1l[h], fa.h, sv, 0, 0, 0);
                }
#pragma unroll
                for (int rg = 0; rg < 4; ++rg) bil[v][nt][rg] = sv[rg] + bv[rg];
            }
        }
    }

    // ---------- i-loop: barrier-free, T frags global->VGPR with 1-step prefetch ----------
    const u8* tb = ws + (size_t)MODE * 1048576 + kt * 4096 + lr * 64 + lq * 16;
    {
        const u8* tp = tb + (size_t)(jh * 32) * 16384;
        short8v Th0 = *(const short8v*)(tp);
        short8v Tl0 = *(const short8v*)(tp + 1024);
        short8v Th1 = *(const short8v*)(tp + 2048);
        short8v Tl1 = *(const short8v*)(tp + 3072);
#pragma unroll 1
        for (int ii = 0; ii < 32; ++ii) {
            const int i = jh * 32 + ii;
            // prefetch next step (ii==31 reads one-past: in-bounds scratch, values unused)
            const u8* tn = tb + (size_t)(i + 1) * 16384;
            const short8v nTh0 = *(const short8v*)(tn);
            const short8v nTl0 = *(const short8v*)(tn + 1024);
            const short8v nTh1 = *(const short8v*)(tn + 2048);
            const short8v nTl1 = *(const short8v*)(tn + 3072);
            const int irow = i * 64, im = i & 31;
            float sU[4], sR[4];
#pragma unroll
            for (int nt = 0; nt < 4; ++nt) {
                const int b = nt * 16 + lr;
                sU[nt] = ((const float*)(sm + SA))[irow + (b ^ im)];
                if (MODE != 1) sR[nt] = ((const float*)(sm + TILE_B))[irow + (b ^ im)];
            }
#pragma unroll
            for (int nt = 0; nt < 4; ++nt) {
                f32x4 S = {0.f, 0.f, 0.f, 0.f};
                S = MFMA16(Th0, Bh[nt][0], S, 0, 0, 0);
                S = MFMA16(Th0, Bl[nt][0], S, 0, 0, 0);
                S = MFMA16(Tl0, Bh[nt][0], S, 0, 0, 0);
                S = MFMA16(Th1, Bh[nt][1], S, 0, 0, 0);
                S = MFMA16(Th1, Bl[nt][1], S, 0, 0, 0);
                S = MFMA16(Tl1, Bh[nt][1], S, 0, 0, 0);
#pragma unroll
                for (int rg = 0; rg < 4; ++rg) {
                    bil[0][nt][rg] += sU[nt] * S[rg];
                    if (MODE != 1) bil[1][nt][rg] += sR[nt] * S[rg];
                }
            }
            Th0 = nTh0; Tl0 = nTl0; Th1 = nTh1; Tl1 = nTl1;
        }
    }

    // ---------- i-half merge (once per pass) ----------
    float* P0 = (float*)(sm + PRE);
    float* P1 = (float*)(sm + PRE + 16384);
    if (jh == 1) {
#pragma unroll
        for (int nt = 0; nt < 4; ++nt)
#pragma unroll
        for (int rg = 0; rg < 4; ++rg) {
            const int k = kt * 16 + lq * 4 + rg, b = nt * 16 + lr;
            P0[k * 64 + b] = bil[0][nt][rg];
            if (MODE != 1) P1[k * 64 + b] = bil[1][nt][rg];
        }
    }
    __syncthreads();

    // ---------- epilogue: jh0 adds partner half, tanh, store ----------
    if (jh == 0) {
#pragma unroll
        for (int nt = 0; nt < 4; ++nt)
#pragma unroll
        for (int rg = 0; rg < 4; ++rg) {
            const int k = kt * 16 + lq * 4 + rg, b = nt * 16 + lr;
            const float u0 = tanhf(bil[0][nt][rg] + P0[k * 64 + b]);
            if (MODE == 0) {
                ((float*)(sm + TILE_A))[k * 64 + (b ^ (k & 31))] = u0;
                const float u1 = tanhf(bil[1][nt][rg] + P1[k * 64 + b]);
                ((float*)(sm + TILE_B))[k * 64 + (b ^ (k & 31))] = u1;
            } else if (MODE == 1) {
                ((float*)(sm + TILE_C))[k * 64 + (b ^ (k & 31))] = u0;
            } else {
                ((float*)(sm + TILE_A))[b * 64 + (k ^ (b & 31))] = u0;
                const float u1 = tanhf(bil[1][nt][rg] + P1[k * 64 + b]);
                ((float*)(sm + TILE_B))[b * 64 + (k ^ (b & 31))] = u1;
            }
        }
    }
    if (MODE == 2) {
        __syncthreads();
#pragma unroll
        for (int r = 0; r < 8; ++r) {              // coalesced float2 store
            const int idx = r * 512 + tid;
            const int b = idx >> 6, k = idx & 63;
            float2 o;
            o.x = ((const float*)(sm + TILE_A))[b * 64 + (k ^ (b & 31))];
            o.y = ((const float*)(sm + TILE_B))[b * 64 + (k ^ (b & 31))];
            *(float2*)(outg + (size_t)(B0 + b) * 128 + k * 2) = o;
        }
    }
}

__global__ __launch_bounds__(512, 4)
void ntn_main(const float* __restrict__ e1, const float* __restrict__ p,
              const float* __restrict__ e2, const float* __restrict__ er,
              const float* __restrict__ bias, const u8* __restrict__ ws,
              float* __restrict__ out)
{
    __shared__ __align__(16) u8 sm[SMB];
    const int tid = threadIdx.x;
    const int l = tid & 63;
    const int w8 = __builtin_amdgcn_readfirstlane(tid >> 6);
    const int kt = w8 & 3, jh = w8 >> 2;
    const int lr = l & 15, lq = l >> 4;
    const int B0 = blockIdx.x * 64;

    // stage transposed f32 tiles: e1^T -> A, er^T -> B, p^T -> C (swizzled, conflict-free)
#pragma unroll
    for (int r = 0; r < 8; ++r) {
        const int idx = r * 512 + tid;
        const int b = idx >> 6, i = idx & 63;
        const int d = i * 64 + (b ^ (i & 31));
        ((float*)(sm + TILE_A))[d] = e1[(size_t)(B0 + b) * 64 + i];
        ((float*)(sm + TILE_B))[d] = er[(size_t)(B0 + b) * 64 + i];
        ((float*)(sm + TILE_C))[d] = p [(size_t)(B0 + b) * 64 + i];
    }

    pass_run<0>(sm, ws, p,  e1, er,     bias, nullptr, B0, kt, jh, lr, lq, tid);
    pass_run<1>(sm, ws, e2, p,  nullptr, bias, nullptr, B0, kt, jh, lr, lq, tid);
    pass_run<2>(sm, ws, nullptr, nullptr, nullptr, bias, out, B0, kt, jh, lr, lq, tid);
}

extern "C" void kernel_launch(void* const* d_in, const int* in_sizes, int n_in,
                              void* d_out, int out_size, void* d_ws, size_t ws_size,
                              hipStream_t stream) {
    const float* e1   = (const float*)d_in[0];
    const float* p    = (const float*)d_in[1];
    const float* e2   = (const float*)d_in[2];
    const float* er   = (const float*)d_in[3];
    const float* T1   = (const float*)d_in[4];
    const float* T2   = (const float*)d_in[5];
    const float* T3   = (const float*)d_in[6];
    const float* W    = (const float*)d_in[7];
    const float* bias = (const float*)d_in[8];

    u8* ws = (u8*)d_ws;
    hipLaunchKernelGGL(presplit_kernel, dim3(3136), dim3(256), 0, stream, T1, T2, T3, W, ws);
    hipLaunchKernelGGL(ntn_main, dim3(BATCH / 64), dim3(512), 0, stream,
                       e1, p, e2, er, bias, (const u8*)ws, (float*)d_out);
}